// Round 1
// baseline (8052.165 us; speedup 1.0000x reference)
//
#include <hip/hip_runtime.h>
#include <hip/hip_bf16.h>

// Problem constants (match the reference)
#define BB   64
#define QQ   256
#define TT   256
#define NC_  256
#define CD   258          // 2 + NC
#define NM   256          // square assignment size (T == Q)
#define BIGF 1000000000.0f

// ---------------------------------------------------------------------------
// Kernel 1: per-(b,q) softmax stats (max and sum of exp(x-max)) over NC=256
// one block of 256 threads per row
// ---------------------------------------------------------------------------
__global__ __launch_bounds__(256) void sm_stats(const float* __restrict__ outs,
                                                float* __restrict__ rmax,
                                                float* __restrict__ rsum) {
    int row = blockIdx.x;            // b*Q + q
    int tid = threadIdx.x;
    float x = outs[(size_t)row * CD + 2 + tid];

    __shared__ float sw[5];
    float m = x;
#pragma unroll
    for (int off = 32; off; off >>= 1) m = fmaxf(m, __shfl_down(m, off, 64));
    if ((tid & 63) == 0) sw[tid >> 6] = m;
    __syncthreads();
    if (tid == 0) sw[4] = fmaxf(fmaxf(sw[0], sw[1]), fmaxf(sw[2], sw[3]));
    __syncthreads();
    float mx = sw[4];

    float s = expf(x - mx);
#pragma unroll
    for (int off = 32; off; off >>= 1) s += __shfl_down(s, off, 64);
    __syncthreads();
    if ((tid & 63) == 0) sw[tid >> 6] = s;
    __syncthreads();
    if (tid == 0) {
        rmax[row] = mx;
        rsum[row] = sw[0] + sw[1] + sw[2] + sw[3];
    }
}

// ---------------------------------------------------------------------------
// Kernel 2: build cost matrix C[b][t][q]  (already transposed vs reference)
// one block of 256 threads (q) per (b,t)
// ---------------------------------------------------------------------------
__global__ __launch_bounds__(256) void build_cost(const float* __restrict__ outs,
                                                  const float* __restrict__ tpos,
                                                  const int* __restrict__ tids,
                                                  const float* __restrict__ rmax,
                                                  const float* __restrict__ rsum,
                                                  float* __restrict__ C) {
    int bt = blockIdx.x;             // b*T + t
    int b  = bt >> 8;
    int q  = threadIdx.x;

    int   id = tids[bt];
    float tx = tpos[2 * bt];
    float ty = tpos[2 * bt + 1];

    const float* orow = outs + (size_t)(b * QQ + q) * CD;
    float dx = orow[0] - tx;
    float dy = orow[1] - ty;
    float d  = sqrtf(dx * dx + dy * dy);
    float bbox = fminf(d, 100.0f);
    if (id <= 0) bbox = 100.0f;

    int   rq  = b * QQ + q;
    float cls = expf(orow[2 + id] - rmax[rq]) / rsum[rq];

    C[(size_t)bt * QQ + q] = bbox - cls;   // bbox + (-prob)
}

// ---------------------------------------------------------------------------
// Kernel 3: Jonker-Volgenant shortest augmenting path, one block per batch.
// Thread j owns column j. Exactly mirrors the reference's update order and
// argmin first-index tie-break.
// ---------------------------------------------------------------------------
__global__ __launch_bounds__(256) void hungarian(const float* __restrict__ Call,
                                                 float* __restrict__ outIdx) {
    const int b = blockIdx.x;
    const int j = threadIdx.x;
    const float* cost = Call + (size_t)b * NM * NM;

    __shared__ float u[NM], v[NM], minv[NM];
    __shared__ int   p[NM + 1], way[NM];
    __shared__ unsigned char used[NM];
    __shared__ int   sj0, sj1;
    __shared__ float sdelta;
    __shared__ float red_v[4];
    __shared__ int   red_i[4];
    __shared__ unsigned char used_ndum;

    u[j] = 0.0f; v[j] = 0.0f; p[j] = -1;
    if (j == 0) p[NM] = -1;
    __syncthreads();

    for (int i = 0; i < NM; ++i) {
        minv[j] = BIGF; way[j] = NM; used[j] = 0;
        if (j == 0) { p[NM] = i; used_ndum = 0; sj0 = NM; }
        __syncthreads();

        while (true) {
            const int j0 = sj0;
            const int i0 = p[j0];
            if (i0 < 0) break;                       // found free column

            const float ui0 = u[i0];
            const bool  uj  = (j == j0) || used[j];  // used AFTER marking j0
            const float cur = cost[i0 * NM + j] - ui0 - v[j];
            if (!uj && cur < minv[j]) { minv[j] = cur; way[j] = j0; }

            float mval = uj ? BIGF : minv[j];
            int   midx = j;
#pragma unroll
            for (int off = 32; off; off >>= 1) {
                float ov = __shfl_down(mval, off, 64);
                int   oi = __shfl_down(midx, off, 64);
                if (ov < mval || (ov == mval && oi < midx)) { mval = ov; midx = oi; }
            }
            if ((j & 63) == 0) { red_v[j >> 6] = mval; red_i[j >> 6] = midx; }
            __syncthreads();
            if (j == 0) {
                float bv = red_v[0]; int bi = red_i[0];
#pragma unroll
                for (int w = 1; w < 4; ++w) {
                    float ov = red_v[w]; int oi = red_i[w];
                    if (ov < bv || (ov == bv && oi < bi)) { bv = ov; bi = oi; }
                }
                sdelta = bv; sj1 = bi;
            }
            __syncthreads();
            const float delta = sdelta;

            // updates (match reference: u scatter-add, v/minv where(used))
            if (uj) {
                v[j] -= delta;
                u[p[j]] += delta;                    // distinct rows, no conflict
                used[j] = 1;                         // persist for next iters
            } else {
                minv[j] -= delta;
            }
            if (j == 0) {
                const bool u256 = used_ndum || (j0 == NM);
                if (u256) u[p[NM]] += delta;         // u[i] += delta
                used_ndum = u256 ? 1 : 0;
                sj0 = sj1;
            }
            __syncthreads();
        }

        // augmenting path flip (serial, tiny)
        if (j == 0) {
            int j0 = sj0;
            while (j0 != NM) {
                int j1 = way[j0];
                p[j0] = p[j1];
                j0 = j1;
            }
        }
        __syncthreads();
    }

    // outputs (as float32): indices[0]=rows, indices[1]=cols
    outIdx[b * TT + j] = (float)j;                   // rows: arange
    int r = p[j];                                    // row assigned to column j
    outIdx[BB * TT + b * TT + r] = (float)j;         // cols[r] = j
}

// ---------------------------------------------------------------------------
extern "C" void kernel_launch(void* const* d_in, const int* in_sizes, int n_in,
                              void* d_out, int out_size, void* d_ws, size_t ws_size,
                              hipStream_t stream) {
    const float* outs = (const float*)d_in[0];   // (B,Q,258) f32
    const float* tpos = (const float*)d_in[1];   // (B,T,2)   f32
    const int*   tids = (const int*)d_in[2];     // (B,T)     i32

    float* out  = (float*)d_out;
    float* C    = out + 2 * BB * TT;             // C region after indices
    float* rmax = (float*)d_ws;                  // B*Q floats
    float* rsum = rmax + BB * QQ;                // B*Q floats

    hipLaunchKernelGGL(sm_stats,   dim3(BB * QQ), dim3(256), 0, stream, outs, rmax, rsum);
    hipLaunchKernelGGL(build_cost, dim3(BB * TT), dim3(256), 0, stream, outs, tpos, tids, rmax, rsum, C);
    hipLaunchKernelGGL(hungarian,  dim3(BB),      dim3(256), 0, stream, C, out);
}

// Round 4
// 3725.440 us; speedup vs baseline: 2.1614x; 2.1614x over previous
//
#include <hip/hip_runtime.h>
#include <hip/hip_bf16.h>

#define BB   64
#define QQ   256
#define TT   256
#define CD   258          // 2 + NC
#define NM   256          // square assignment size
#define BIGF 1000000000.0f

// ---------------------------------------------------------------------------
// Kernel 1: per-(b,q) softmax stats (max and sum of exp(x-max)) over NC=256
// ---------------------------------------------------------------------------
__global__ __launch_bounds__(256) void sm_stats(const float* __restrict__ outs,
                                                float* __restrict__ rmax,
                                                float* __restrict__ rsum) {
    int row = blockIdx.x;            // b*Q + q
    int tid = threadIdx.x;
    float x = outs[(size_t)row * CD + 2 + tid];

    __shared__ float sw[5];
    float m = x;
#pragma unroll
    for (int off = 32; off; off >>= 1) m = fmaxf(m, __shfl_down(m, off, 64));
    if ((tid & 63) == 0) sw[tid >> 6] = m;
    __syncthreads();
    if (tid == 0) sw[4] = fmaxf(fmaxf(sw[0], sw[1]), fmaxf(sw[2], sw[3]));
    __syncthreads();
    float mx = sw[4];

    float s = expf(x - mx);
#pragma unroll
    for (int off = 32; off; off >>= 1) s += __shfl_down(s, off, 64);
    __syncthreads();
    if ((tid & 63) == 0) sw[tid >> 6] = s;
    __syncthreads();
    if (tid == 0) {
        rmax[row] = mx;
        rsum[row] = sw[0] + sw[1] + sw[2] + sw[3];
    }
}

// ---------------------------------------------------------------------------
// Kernel 2: build cost matrix C[b][t][q]
// ---------------------------------------------------------------------------
__global__ __launch_bounds__(256) void build_cost(const float* __restrict__ outs,
                                                  const float* __restrict__ tpos,
                                                  const int* __restrict__ tids,
                                                  const float* __restrict__ rmax,
                                                  const float* __restrict__ rsum,
                                                  float* __restrict__ C) {
    int bt = blockIdx.x;             // b*T + t
    int b  = bt >> 8;
    int q  = threadIdx.x;

    int   id = tids[bt];
    float tx = tpos[2 * bt];
    float ty = tpos[2 * bt + 1];

    const float* orow = outs + (size_t)(b * QQ + q) * CD;
    float dx = orow[0] - tx;
    float dy = orow[1] - ty;
    float d  = sqrtf(dx * dx + dy * dy);
    float bbox = fminf(d, 100.0f);
    if (id <= 0) bbox = 100.0f;

    int   rq  = b * QQ + q;
    float cls = expf(orow[2 + id] - rmax[rq]) / rsum[rq];

    C[(size_t)bt * QQ + q] = bbox - cls;
}

// ---------------------------------------------------------------------------
// Kernel 3: EXACT reference JV (sequential rows, u=v=0 init, first-index
// argmin) — but one wave per batch, 4 columns/lane, all Dijkstra state in
// registers, shuffle-only reductions, no barriers/LDS in the inner loop.
// Arithmetic order matches the reference bitwise (duplicate-row ties in C
// make the optimum non-unique; tie-breaks must replicate exactly).
// ---------------------------------------------------------------------------
__device__ __forceinline__ int sel4i(const int a[4], int s) {
    int r = a[0];
    r = (s == 1) ? a[1] : r;
    r = (s == 2) ? a[2] : r;
    r = (s == 3) ? a[3] : r;
    return r;
}
__device__ __forceinline__ float sel4f(const float a[4], int s) {
    float r = a[0];
    r = (s == 1) ? a[1] : r;
    r = (s == 2) ? a[2] : r;
    r = (s == 3) ? a[3] : r;
    return r;
}

__global__ __launch_bounds__(64) void jv_solve(const float* __restrict__ Call,
                                               float* __restrict__ outIdx) {
    const int b    = blockIdx.x;
    const int lane = threadIdx.x;
    const float* cost = Call + (size_t)b * NM * NM;

    __shared__ float u_lds[NM + 1];
    __shared__ int   p_lds[NM + 1];
    __shared__ int   way_lds[NM];

    for (int k = lane; k <= NM; k += 64) {
        u_lds[k] = 0.0f;
        p_lds[k] = -1;
        if (k < NM) way_lds[k] = NM;
    }
    __syncthreads();

    float v[4] = {0.0f, 0.0f, 0.0f, 0.0f};   // column duals, persist across scans

    for (int i = 0; i < NM; ++i) {
        if (lane == 0) p_lds[NM] = i;

        // p[j] and u[p[j]] are static during one scan (matching injective;
        // rows are expanded before their u gets this scan's delta updates).
        int   pj[4];
        float ureg[4];
#pragma unroll
        for (int s = 0; s < 4; ++s) {
            pj[s]   = p_lds[lane * 4 + s];
            ureg[s] = (pj[s] >= 0) ? u_lds[pj[s]] : 0.0f;
        }
        float uof[4] = {ureg[0], ureg[1], ureg[2], ureg[3]};  // scan-start copy
        float minv[4] = {BIGF, BIGF, BIGF, BIGF};
        int   way[4]  = {NM, NM, NM, NM};
        unsigned usedm = 0;
        float ui = 0.0f;                 // u[i] == 0 at its own scan start
        int   j0 = NM;
        int   i0 = i;
        float u0 = 0.0f;

        while (true) {
            // mark j0 used (reference marks at body start, before minv update)
            if ((j0 >> 2) == lane) usedm |= 1u << (j0 & 3);

            float4 cr = *(const float4*)(cost + (size_t)i0 * NM + lane * 4);
            float c4[4] = {cr.x, cr.y, cr.z, cr.w};
#pragma unroll
            for (int s = 0; s < 4; ++s) {
                float cur = c4[s] - u0 - v[s];
                bool  un  = !(usedm & (1u << s));
                if (un && cur < minv[s]) { minv[s] = cur; way[s] = j0; }
            }
            // local argmin over unused slots (first-index tie-break within lane)
            float lv = BIGF; int ls = 0;
#pragma unroll
            for (int s = 0; s < 4; ++s) {
                float c = (usedm & (1u << s)) ? BIGF : minv[s];
                if (c < lv) { lv = c; ls = s; }
            }
            // wave-wide min; ballot picks lowest lane -> global first-index
            float wv = lv;
#pragma unroll
            for (int off = 1; off < 64; off <<= 1)
                wv = fminf(wv, __shfl_xor(wv, off, 64));
            unsigned long long mm = __ballot(lv == wv);
            int flane = __ffsll(mm) - 1;
            int j1    = __shfl(lane * 4 + ls, flane, 64);
            float delta = wv;

            int   s1  = j1 & 3, l1 = j1 >> 2;
            int   i0n = __shfl(sel4i(pj, s1), l1, 64);
            float u0n = __shfl(sel4f(uof, s1), l1, 64);

            // updates, same order/arithmetic as reference
            ui += delta;                                  // u[i] += delta (j=NDUM used)
#pragma unroll
            for (int s = 0; s < 4; ++s) {
                if (usedm & (1u << s)) { v[s] -= delta; ureg[s] += delta; }
                else                   { minv[s] -= delta; }
            }
            j0 = j1;
            if (i0n < 0) break;          // free column found
            i0 = i0n; u0 = u0n;
        }

        // write back per-scan state
#pragma unroll
        for (int s = 0; s < 4; ++s) {
            way_lds[lane * 4 + s] = way[s];
            if (usedm & (1u << s)) u_lds[pj[s]] = ureg[s];  // distinct rows
        }
        if (lane == 0) u_lds[i] = ui;
        __syncthreads();

        // augmenting path flip (tiny serial walk)
        if (lane == 0) {
            int jj = j0;
            while (jj != NM) {
                int j1w = way_lds[jj];
                p_lds[jj] = p_lds[j1w];
                jj = j1w;
            }
        }
        __syncthreads();
    }

    // outputs as float32: indices[0]=rows (arange), indices[1]=cols
#pragma unroll
    for (int s = 0; s < 4; ++s) {
        int j = lane * 4 + s;
        outIdx[b * TT + j] = (float)j;
        int r = p_lds[j];
        outIdx[BB * TT + b * TT + r] = (float)j;
    }
}

// ---------------------------------------------------------------------------
extern "C" void kernel_launch(void* const* d_in, const int* in_sizes, int n_in,
                              void* d_out, int out_size, void* d_ws, size_t ws_size,
                              hipStream_t stream) {
    const float* outs = (const float*)d_in[0];   // (B,Q,258) f32
    const float* tpos = (const float*)d_in[1];   // (B,T,2)   f32
    const int*   tids = (const int*)d_in[2];     // (B,T)     i32

    float* out  = (float*)d_out;
    float* C    = out + 2 * BB * TT;
    float* rmax = (float*)d_ws;
    float* rsum = rmax + BB * QQ;

    hipLaunchKernelGGL(sm_stats,   dim3(BB * QQ), dim3(256), 0, stream, outs, rmax, rsum);
    hipLaunchKernelGGL(build_cost, dim3(BB * TT), dim3(256), 0, stream, outs, tpos, tids, rmax, rsum, C);
    hipLaunchKernelGGL(jv_solve,   dim3(BB),      dim3(64),  0, stream, C, out);
}

// Round 5
// 2861.237 us; speedup vs baseline: 2.8142x; 1.3020x over previous
//
#include <hip/hip_runtime.h>
#include <hip/hip_bf16.h>

#define BB   64
#define QQ   256
#define TT   256
#define CD   258          // 2 + NC
#define NM   256          // square assignment size
#define BIGF 1000000000.0f
#define WPB  8            // waves (batches) per block

// ---------------------------------------------------------------------------
// Kernel 1: per-(b,q) softmax stats (max and sum of exp(x-max)) over NC=256
// ---------------------------------------------------------------------------
__global__ __launch_bounds__(256) void sm_stats(const float* __restrict__ outs,
                                                float* __restrict__ rmax,
                                                float* __restrict__ rsum) {
    int row = blockIdx.x;            // b*Q + q
    int tid = threadIdx.x;
    float x = outs[(size_t)row * CD + 2 + tid];

    __shared__ float sw[5];
    float m = x;
#pragma unroll
    for (int off = 32; off; off >>= 1) m = fmaxf(m, __shfl_down(m, off, 64));
    if ((tid & 63) == 0) sw[tid >> 6] = m;
    __syncthreads();
    if (tid == 0) sw[4] = fmaxf(fmaxf(sw[0], sw[1]), fmaxf(sw[2], sw[3]));
    __syncthreads();
    float mx = sw[4];

    float s = expf(x - mx);
#pragma unroll
    for (int off = 32; off; off >>= 1) s += __shfl_down(s, off, 64);
    __syncthreads();
    if ((tid & 63) == 0) sw[tid >> 6] = s;
    __syncthreads();
    if (tid == 0) {
        rmax[row] = mx;
        rsum[row] = sw[0] + sw[1] + sw[2] + sw[3];
    }
}

// ---------------------------------------------------------------------------
// Kernel 2: build cost matrix C[b][t][q]
// ---------------------------------------------------------------------------
__global__ __launch_bounds__(256) void build_cost(const float* __restrict__ outs,
                                                  const float* __restrict__ tpos,
                                                  const int* __restrict__ tids,
                                                  const float* __restrict__ rmax,
                                                  const float* __restrict__ rsum,
                                                  float* __restrict__ C) {
    int bt = blockIdx.x;             // b*T + t
    int b  = bt >> 8;
    int q  = threadIdx.x;

    int   id = tids[bt];
    float tx = tpos[2 * bt];
    float ty = tpos[2 * bt + 1];

    const float* orow = outs + (size_t)(b * QQ + q) * CD;
    float dx = orow[0] - tx;
    float dy = orow[1] - ty;
    float d  = sqrtf(dx * dx + dy * dy);
    float bbox = fminf(d, 100.0f);
    if (id <= 0) bbox = 100.0f;

    int   rq  = b * QQ + q;
    float cls = expf(orow[2 + id] - rmax[rq]) / rsum[rq];

    C[(size_t)bt * QQ + q] = bbox - cls;
}

// ---------------------------------------------------------------------------
// Kernel 3: EXACT reference JV, one batch per WAVE (8 waves/block, no
// barriers). Inner loop: zero DS ops — DPP wave-min + readlane payload
// fetch, rotated loop prefetches the next cost row before delta updates.
// Tie-breaks replicate the reference bitwise (argmin first-index).
// ---------------------------------------------------------------------------
template <int CTRL, int RM>
__device__ __forceinline__ float dppmin(float x) {
    int y = __builtin_amdgcn_update_dpp(__float_as_int(x), __float_as_int(x),
                                        CTRL, RM, 0xF, false);
    return fminf(x, __int_as_float(y));
}

__global__ __launch_bounds__(64 * WPB) void jv_solve(const float* __restrict__ Call,
                                                     float* __restrict__ outIdx) {
    const int wid  = threadIdx.x >> 6;               // wave id in block
    const int lane = threadIdx.x & 63;
    const int b    = blockIdx.x * WPB + wid;         // batch for this wave
    const float* cost = Call + (size_t)b * NM * NM;

    __shared__ float u_l[WPB][NM + 1];
    __shared__ int   p_l[WPB][NM + 1];
    __shared__ int   way_l[WPB][NM];

    float* u_s   = u_l[wid];
    int*   p_s   = p_l[wid];
    int*   way_s = way_l[wid];

    for (int k = lane; k <= NM; k += 64) {
        u_s[k] = 0.0f;
        p_s[k] = -1;
        if (k < NM) way_s[k] = NM;
    }
    // no barrier needed: all LDS state is wave-private

    float v[4] = {0.0f, 0.0f, 0.0f, 0.0f};   // column duals, persist

    for (int i = 0; i < NM; ++i) {
        // prefetch first row of this scan (row i) early
        float4 cr = *(const float4*)(cost + (size_t)i * NM + lane * 4);

        if (lane == 0) p_s[NM] = i;
        // p[j], u[p[j]] are static during one scan
        int   pj[4];
        float ureg[4];
#pragma unroll
        for (int s = 0; s < 4; ++s) {
            pj[s]   = p_s[lane * 4 + s];
            ureg[s] = (pj[s] >= 0) ? u_s[pj[s]] : 0.0f;
        }
        const float uof0 = ureg[0], uof1 = ureg[1], uof2 = ureg[2], uof3 = ureg[3];
        float minv[4] = {BIGF, BIGF, BIGF, BIGF};
        int   way[4]  = {NM, NM, NM, NM};
        unsigned usedm = 0;
        float ui = 0.0f;
        int   j0 = NM;
        float u0 = 0.0f;

        while (true) {
            // mark j0 used (owner lane), before minv update — as reference
            if ((j0 >> 2) == lane) usedm |= 1u << (j0 & 3);

            float c4[4] = {cr.x, cr.y, cr.z, cr.w};
#pragma unroll
            for (int s = 0; s < 4; ++s) {
                float cur = c4[s] - u0 - v[s];
                bool  un  = !(usedm & (1u << s));
                if (un && cur < minv[s]) { minv[s] = cur; way[s] = j0; }
            }

            // local argmin over 4 slots with payload (first-index tie-break)
            float cand[4];
#pragma unroll
            for (int s = 0; s < 4; ++s)
                cand[s] = (usedm & (1u << s)) ? BIGF : minv[s];
            float cA = cand[0]; int lsA = 0; int pA = pj[0]; float uA = uof0;
            if (cand[1] < cA) { cA = cand[1]; lsA = 1; pA = pj[1]; uA = uof1; }
            float cB = cand[2]; int lsB = 2; int pB = pj[2]; float uB = uof2;
            if (cand[3] < cB) { cB = cand[3]; lsB = 3; pB = pj[3]; uB = uof3; }
            if (cB < cA)      { cA = cB;      lsA = lsB; pA = pB;  uA = uB;  }

            // wave-wide min via DPP (VALU pipe only), result in lane 63
            float x = cA;
            x = dppmin<0x111, 0xF>(x);   // row_shr:1
            x = dppmin<0x112, 0xF>(x);   // row_shr:2
            x = dppmin<0x114, 0xF>(x);   // row_shr:4
            x = dppmin<0x118, 0xF>(x);   // row_shr:8
            x = dppmin<0x142, 0xA>(x);   // row_bcast:15 -> rows 1,3
            x = dppmin<0x143, 0xC>(x);   // row_bcast:31 -> rows 2,3
            float wv = __int_as_float(__builtin_amdgcn_readlane(__float_as_int(x), 63));

            unsigned long long mm = __ballot(cA == wv);
            int flane = __ffsll(mm) - 1;             // lowest tied lane
            // fetch winner payload: packed (pj+1, ls) and uof
            int   pk  = ((pA + 1) << 2) | lsA;
            int   wpk = __builtin_amdgcn_readlane(pk, flane);
            float u0n = __int_as_float(__builtin_amdgcn_readlane(__float_as_int(uA), flane));
            int   i0n = (wpk >> 2) - 1;
            int   j1  = flane * 4 + (wpk & 3);
            float delta = wv;

            // prefetch next row before the delta updates (overlap L2 latency)
            if (i0n >= 0)
                cr = *(const float4*)(cost + (size_t)i0n * NM + lane * 4);

            // updates, same order/arithmetic as reference
            ui += delta;
#pragma unroll
            for (int s = 0; s < 4; ++s) {
                if (usedm & (1u << s)) { v[s] -= delta; ureg[s] += delta; }
                else                   { minv[s] -= delta; }
            }
            j0 = j1;
            if (i0n < 0) break;
            u0 = u0n;
        }

        // write back per-scan state (wave-private LDS)
#pragma unroll
        for (int s = 0; s < 4; ++s) {
            way_s[lane * 4 + s] = way[s];
            if (usedm & (1u << s)) u_s[pj[s]] = ureg[s];
        }
        if (lane == 0) {
            u_s[i] = ui;
            // augmenting path flip
            int jj = j0;
            while (jj != NM) {
                int j1w = way_s[jj];
                p_s[jj] = p_s[j1w];
                jj = j1w;
            }
        }
    }

    // outputs as float32: indices[0]=rows (arange), indices[1]=cols
#pragma unroll
    for (int s = 0; s < 4; ++s) {
        int j = lane * 4 + s;
        outIdx[b * TT + j] = (float)j;
        int r = p_s[j];
        outIdx[BB * TT + b * TT + r] = (float)j;
    }
}

// ---------------------------------------------------------------------------
extern "C" void kernel_launch(void* const* d_in, const int* in_sizes, int n_in,
                              void* d_out, int out_size, void* d_ws, size_t ws_size,
                              hipStream_t stream) {
    const float* outs = (const float*)d_in[0];   // (B,Q,258) f32
    const float* tpos = (const float*)d_in[1];   // (B,T,2)   f32
    const int*   tids = (const int*)d_in[2];     // (B,T)     i32

    float* out  = (float*)d_out;
    float* C    = out + 2 * BB * TT;
    float* rmax = (float*)d_ws;
    float* rsum = rmax + BB * QQ;

    hipLaunchKernelGGL(sm_stats,   dim3(BB * QQ), dim3(256), 0, stream, outs, rmax, rsum);
    hipLaunchKernelGGL(build_cost, dim3(BB * TT), dim3(256), 0, stream, outs, tpos, tids, rmax, rsum, C);
    hipLaunchKernelGGL(jv_solve,   dim3(BB / WPB), dim3(64 * WPB), 0, stream, C, out);
}

// Round 6
// 2534.421 us; speedup vs baseline: 3.1771x; 1.1290x over previous
//
#include <hip/hip_runtime.h>
#include <hip/hip_bf16.h>

#define BB   64
#define QQ   256
#define TT   256
#define CD   258          // 2 + NC
#define NM   256          // square assignment size
#define BIGF 1000000000.0f
#define LROWS 128         // rows cached in LDS (128 KB)

// ---------------------------------------------------------------------------
// Kernel 1: per-(b,q) softmax stats (max and sum of exp(x-max)) over NC=256
// ---------------------------------------------------------------------------
__global__ __launch_bounds__(256) void sm_stats(const float* __restrict__ outs,
                                                float* __restrict__ rmax,
                                                float* __restrict__ rsum) {
    int row = blockIdx.x;            // b*Q + q
    int tid = threadIdx.x;
    float x = outs[(size_t)row * CD + 2 + tid];

    __shared__ float sw[5];
    float m = x;
#pragma unroll
    for (int off = 32; off; off >>= 1) m = fmaxf(m, __shfl_down(m, off, 64));
    if ((tid & 63) == 0) sw[tid >> 6] = m;
    __syncthreads();
    if (tid == 0) sw[4] = fmaxf(fmaxf(sw[0], sw[1]), fmaxf(sw[2], sw[3]));
    __syncthreads();
    float mx = sw[4];

    float s = expf(x - mx);
#pragma unroll
    for (int off = 32; off; off >>= 1) s += __shfl_down(s, off, 64);
    __syncthreads();
    if ((tid & 63) == 0) sw[tid >> 6] = s;
    __syncthreads();
    if (tid == 0) {
        rmax[row] = mx;
        rsum[row] = sw[0] + sw[1] + sw[2] + sw[3];
    }
}

// ---------------------------------------------------------------------------
// Kernel 2: build cost matrix C[b][t][q]
// ---------------------------------------------------------------------------
__global__ __launch_bounds__(256) void build_cost(const float* __restrict__ outs,
                                                  const float* __restrict__ tpos,
                                                  const int* __restrict__ tids,
                                                  const float* __restrict__ rmax,
                                                  const float* __restrict__ rsum,
                                                  float* __restrict__ C) {
    int bt = blockIdx.x;             // b*T + t
    int b  = bt >> 8;
    int q  = threadIdx.x;

    int   id = tids[bt];
    float tx = tpos[2 * bt];
    float ty = tpos[2 * bt + 1];

    const float* orow = outs + (size_t)(b * QQ + q) * CD;
    float dx = orow[0] - tx;
    float dy = orow[1] - ty;
    float d  = sqrtf(dx * dx + dy * dy);
    float bbox = fminf(d, 100.0f);
    if (id <= 0) bbox = 100.0f;

    int   rq  = b * QQ + q;
    float cls = expf(orow[2 + id] - rmax[rq]) / rsum[rq];

    C[(size_t)bt * QQ + q] = bbox - cls;
}

// ---------------------------------------------------------------------------
// Kernel 3: EXACT reference JV, ONE WAVE PER BLOCK (own CU: no VALU issue
// contention). Rows 0..127 cached in 128KB dynamic LDS (bit-identical copy);
// inner loop has zero cross-lane DS ops (DPP min + readlane payloads).
// Tie-breaks replicate the reference bitwise (argmin first-index).
// ---------------------------------------------------------------------------
template <int CTRL, int RM>
__device__ __forceinline__ float dppmin(float x) {
    int y = __builtin_amdgcn_update_dpp(__float_as_int(x), __float_as_int(x),
                                        CTRL, RM, 0xF, false);
    return fminf(x, __int_as_float(y));
}

__global__ __launch_bounds__(64) void jv_solve(const float* __restrict__ Call,
                                               float* __restrict__ outIdx) {
    const int b    = blockIdx.x;
    const int lane = threadIdx.x;
    const float* cost = Call + (size_t)b * NM * NM;

    __shared__ float u_s[NM + 1];
    __shared__ int   p_s[NM + 1];
    __shared__ int   way_s[NM];
    extern __shared__ float crow[];          // [LROWS][NM] = 128 KB

    // stage rows 0..LROWS-1 into LDS (bit-identical copy)
#pragma unroll 4
    for (int r = 0; r < LROWS; ++r) {
        float4 x = *(const float4*)(cost + (size_t)r * NM + lane * 4);
        *(float4*)(crow + r * NM + lane * 4) = x;
    }

    for (int k = lane; k <= NM; k += 64) {
        u_s[k] = 0.0f;
        p_s[k] = -1;
        if (k < NM) way_s[k] = NM;
    }
    // single wave: lockstep, no barriers needed anywhere

    float v[4] = {0.0f, 0.0f, 0.0f, 0.0f};   // column duals, persist

    for (int i = 0; i < NM; ++i) {
        // prefetch first row of this scan (row i)
        float4 cr;
        if (i < LROWS) cr = *(const float4*)(crow + i * NM + lane * 4);
        else           cr = *(const float4*)(cost + (size_t)i * NM + lane * 4);

        if (lane == 0) p_s[NM] = i;
        // p[j], u[p[j]] static during one scan
        int   pj[4];
        float ureg[4];
#pragma unroll
        for (int s = 0; s < 4; ++s) {
            pj[s]   = p_s[lane * 4 + s];
            ureg[s] = (pj[s] >= 0) ? u_s[pj[s]] : 0.0f;
        }
        const float uof0 = ureg[0], uof1 = ureg[1], uof2 = ureg[2], uof3 = ureg[3];
        float minv[4] = {BIGF, BIGF, BIGF, BIGF};
        int   way[4]  = {NM, NM, NM, NM};
        unsigned usedm = 0;
        float ui = 0.0f;
        int   j0 = NM;
        float u0 = 0.0f;

        while (true) {
            // mark j0 used (owner lane), before minv update — as reference
            if ((j0 >> 2) == lane) usedm |= 1u << (j0 & 3);

            float c4[4] = {cr.x, cr.y, cr.z, cr.w};
#pragma unroll
            for (int s = 0; s < 4; ++s) {
                float cur = c4[s] - u0 - v[s];
                bool  un  = !(usedm & (1u << s));
                if (un && cur < minv[s]) { minv[s] = cur; way[s] = j0; }
            }

            // local argmin over 4 slots with payload (first-index tie-break)
            float cand[4];
#pragma unroll
            for (int s = 0; s < 4; ++s)
                cand[s] = (usedm & (1u << s)) ? BIGF : minv[s];
            float cA = cand[0]; int lsA = 0; int pA = pj[0]; float uA = uof0;
            if (cand[1] < cA) { cA = cand[1]; lsA = 1; pA = pj[1]; uA = uof1; }
            float cB = cand[2]; int lsB = 2; int pB = pj[2]; float uB = uof2;
            if (cand[3] < cB) { cB = cand[3]; lsB = 3; pB = pj[3]; uB = uof3; }
            if (cB < cA)      { cA = cB;      lsA = lsB; pA = pB;  uA = uB;  }

            // wave-wide min via DPP (VALU pipe only), result in lane 63
            float x = cA;
            x = dppmin<0x111, 0xF>(x);   // row_shr:1
            x = dppmin<0x112, 0xF>(x);   // row_shr:2
            x = dppmin<0x114, 0xF>(x);   // row_shr:4
            x = dppmin<0x118, 0xF>(x);   // row_shr:8
            x = dppmin<0x142, 0xA>(x);   // row_bcast:15 -> rows 1,3
            x = dppmin<0x143, 0xC>(x);   // row_bcast:31 -> rows 2,3
            float wv = __int_as_float(__builtin_amdgcn_readlane(__float_as_int(x), 63));

            unsigned long long mm = __ballot(cA == wv);
            int flane = __ffsll(mm) - 1;             // lowest tied lane
            int   pk  = ((pA + 1) << 2) | lsA;       // packed (pj+1, slot)
            int   wpk = __builtin_amdgcn_readlane(pk, flane);
            float u0n = __int_as_float(__builtin_amdgcn_readlane(__float_as_int(uA), flane));
            int   i0n = (wpk >> 2) - 1;
            int   j1  = flane * 4 + (wpk & 3);
            float delta = wv;

            // prefetch next row before the delta updates (overlap latency)
            if (i0n >= 0) {
                if (i0n < LROWS) cr = *(const float4*)(crow + i0n * NM + lane * 4);
                else             cr = *(const float4*)(cost + (size_t)i0n * NM + lane * 4);
            }

            // updates, same order/arithmetic as reference
            ui += delta;
#pragma unroll
            for (int s = 0; s < 4; ++s) {
                if (usedm & (1u << s)) { v[s] -= delta; ureg[s] += delta; }
                else                   { minv[s] -= delta; }
            }
            j0 = j1;
            if (i0n < 0) break;
            u0 = u0n;
        }

        // write back per-scan state
#pragma unroll
        for (int s = 0; s < 4; ++s) {
            way_s[lane * 4 + s] = way[s];
            if (usedm & (1u << s)) u_s[pj[s]] = ureg[s];
        }
        if (lane == 0) {
            u_s[i] = ui;
            // augmenting path flip
            int jj = j0;
            while (jj != NM) {
                int j1w = way_s[jj];
                p_s[jj] = p_s[j1w];
                jj = j1w;
            }
        }
    }

    // outputs as float32: indices[0]=rows (arange), indices[1]=cols
#pragma unroll
    for (int s = 0; s < 4; ++s) {
        int j = lane * 4 + s;
        outIdx[b * TT + j] = (float)j;
        int r = p_s[j];
        outIdx[BB * TT + b * TT + r] = (float)j;
    }
}

// ---------------------------------------------------------------------------
extern "C" void kernel_launch(void* const* d_in, const int* in_sizes, int n_in,
                              void* d_out, int out_size, void* d_ws, size_t ws_size,
                              hipStream_t stream) {
    const float* outs = (const float*)d_in[0];   // (B,Q,258) f32
    const float* tpos = (const float*)d_in[1];   // (B,T,2)   f32
    const int*   tids = (const int*)d_in[2];     // (B,T)     i32

    float* out  = (float*)d_out;
    float* C    = out + 2 * BB * TT;
    float* rmax = (float*)d_ws;
    float* rsum = rmax + BB * QQ;

    hipLaunchKernelGGL(sm_stats,   dim3(BB * QQ), dim3(256), 0, stream, outs, rmax, rsum);
    hipLaunchKernelGGL(build_cost, dim3(BB * TT), dim3(256), 0, stream, outs, tpos, tids, rmax, rsum, C);
    hipLaunchKernelGGL(jv_solve,   dim3(BB),      dim3(64),
                       LROWS * NM * sizeof(float), stream, C, out);
}